// Round 6
// baseline (404.501 us; speedup 1.0000x reference)
//
#include <hip/hip_runtime.h>

typedef unsigned short u16;
typedef unsigned int   u32;
typedef _Float16 f16;
typedef _Float16 f16x8 __attribute__((ext_vector_type(8)));
typedef _Float16 f16x4 __attribute__((ext_vector_type(4)));
typedef float    f32x4 __attribute__((ext_vector_type(4)));

#define BQ 8
#define NQ 8192
#define MQ 64
#define SEGS (BQ*MQ)        /* 512 */
#define MAXCHUNK 3584
#define KBA 10              /* k-blocks in concat(h0,h2) = 320/32 */
#define NCOLS_D 4608        /* 9*512 cols for KNN module, layout [kk][seg] */

/* ---- workspace layout (bytes) ---- */
#define OFF_IDX      (size_t)0
#define OFF_PERM     (size_t)786432
#define OFF_CNT      (size_t)1572864
#define OFF_SUMS     (size_t)1574912
#define OFF_OFFS     (size_t)1581056
#define OFF_CURSOR   (size_t)1583360
#define OFF_NCHUNK   (size_t)1585408
#define OFF_CHUNKTAB (size_t)1585664
#define OFF_MEAN     (size_t)1614336
#define OFF_FALLBACK (size_t)1620480
#define OFF_NODEMAX  (size_t)1632768
#define OFF_CENTER   (size_t)2419200
#define OFF_W1P      (size_t)2425344
#define OFF_W2P      (size_t)2441728
#define OFF_W3P      (size_t)2507264
#define OFF_KNW0P    (size_t)2753024
#define OFF_KNW1P    (size_t)3179008
#define OFF_FINW0P   (size_t)3703296
#define OFF_FINW1P   (size_t)4538880
#define OFF_AUG      (size_t)6111744
#define OFF_MID1     (size_t)9945600
#define OFF_KEIN     (size_t)19382784
#define OFF_MIDE     (size_t)19939840

/* ---------------- kernel W: all weight packs (A-fragment layout, f16) ------------------- */
__device__ __forceinline__ void wpack(const float* __restrict__ W, f16* __restrict__ out,
                                      int K, int KB, int NF, int idx) {
  int e  = idx & 7;
  int l  = (idx >> 3) & 63;
  int kb = (idx >> 9) % KB;
  int rt = idx / (KB << 9);
  int row = rt * 16 + (l & 15);
  int c = kb * 32 + ((l >> 4) << 3) + e;
  int oc;
  if (NF < 0) oc = (c < K) ? c : -1;
  else        oc = (c < NF) ? (3 + c) : ((c < NF + 3) ? (c - NF) : -1);
  out[idx] = (oc >= 0) ? (f16)W[row * K + oc] : (f16)0.f;
}
__global__ __launch_bounds__(256) void kW(
    const float* pr_w1, const float* pr_w2, const float* pr_w3,
    const float* knn_w0, const float* knn_w1, const float* fin_w0, const float* fin_w1,
    f16* w1p, f16* w2p, f16* w3p, f16* knw0p, f16* knw1p, f16* finw0p, f16* finw1p) {
  int blk = blockIdx.x;
  int t = threadIdx.x;
  if (blk < 32)        wpack(pr_w1,  w1p,   64,  2, -1, blk * 256 + t);
  else if (blk < 160)  wpack(pr_w2,  w2p,  128,  4, -1, (blk - 32) * 256 + t);
  else if (blk < 640)  wpack(pr_w3,  w3p,  320, 10, -1, (blk - 160) * 256 + t);
  else if (blk < 1472) wpack(knn_w0, knw0p, 387, 13, 384, (blk - 640) * 256 + t);
  else if (blk < 2496) wpack(knn_w1, knw1p, 512, 16, -1, (blk - 1472) * 256 + t);
  else if (blk < 4128) wpack(fin_w0, finw0p, 515, 17, 512, (blk - 2496) * 256 + t);
  else                 wpack(fin_w1, finw1p, 768, 24, -1, (blk - 4128) * 256 + t);
}

/* ---------------- kernel A: top-3 nearest SOM nodes + LDS-binned count/sum ------------- */
__global__ __launch_bounds__(256) void kA(const float* __restrict__ x, const float* __restrict__ node,
                                          int* __restrict__ idx_buf, int* __restrict__ cnt,
                                          float* __restrict__ sums) {
#pragma clang fp contract(off)
  __shared__ float ns[3][64];
  __shared__ int cbin[64];
  __shared__ float sbin[3][64];
  int b = blockIdx.y;
  int t = threadIdx.x;
  if (t < 192) { int c = t >> 6, m = t & 63; ns[c][m] = node[(b * 3 + c) * 64 + m]; }
  if (t < 64) { cbin[t] = 0; sbin[0][t] = 0.f; sbin[1][t] = 0.f; sbin[2][t] = 0.f; }
  __syncthreads();
  int n = blockIdx.x * 256 + t;
  float x0 = x[(b * 3 + 0) * NQ + n];
  float x1 = x[(b * 3 + 1) * NQ + n];
  float x2 = x[(b * 3 + 2) * NQ + n];
  float d0 = 3.4e38f, d1 = 3.4e38f, d2 = 3.4e38f;
  int i0 = 0, i1 = 0, i2 = 0;
  for (int m = 0; m < 64; ++m) {
    float da = ns[0][m] - x0;
    float db = ns[1][m] - x1;
    float dc = ns[2][m] - x2;
    float d = da * da + db * db + dc * dc;
    if (d < d0)      { d2 = d1; i2 = i1; d1 = d0; i1 = i0; d0 = d; i0 = m; }
    else if (d < d1) { d2 = d1; i2 = i1; d1 = d;  i1 = m; }
    else if (d < d2) { d2 = d;  i2 = m; }
  }
  int base = (b * NQ + n) * 3;
  idx_buf[base + 0] = i0; idx_buf[base + 1] = i1; idx_buf[base + 2] = i2;
  int ms[3] = {i0, i1, i2};
  #pragma unroll
  for (int j = 0; j < 3; ++j) {
    int m = ms[j];
    atomicAdd(&cbin[m], 1);
    atomicAdd(&sbin[0][m], x0);
    atomicAdd(&sbin[1][m], x1);
    atomicAdd(&sbin[2][m], x2);
  }
  __syncthreads();
  if (t < 64 && cbin[t] > 0) {
    atomicAdd(&cnt[b * 64 + t], cbin[t]);
    atomicAdd(&sums[(b * 64 + t) * 3 + 0], sbin[0][t]);
    atomicAdd(&sums[(b * 64 + t) * 3 + 1], sbin[1][t]);
    atomicAdd(&sums[(b * 64 + t) * 3 + 2], sbin[2][t]);
  }
}

/* ---------------- kernel B: scans, chunk table, means, centers, kein center-rows -------- */
__global__ __launch_bounds__(256) void kB(const int* __restrict__ cnt, const float* __restrict__ sums,
                                          int* __restrict__ offs, int* __restrict__ cursor,
                                          int* __restrict__ nchunks, int* __restrict__ chunk_tab,
                                          float* __restrict__ mean, const int* __restrict__ knn_I,
                                          float* __restrict__ centerb, f16* __restrict__ keinP) {
  __shared__ int sps[256], spc[256];
  int t = threadIdx.x;
  int c0 = cnt[2 * t], c1 = cnt[2 * t + 1];
  sps[t] = c0 + c1;
  spc[t] = ((c0 + 63) >> 6) + ((c1 + 63) >> 6);
  __syncthreads();
  for (int d = 1; d < 256; d <<= 1) {
    int a = 0, q = 0;
    if (t >= d) { a = sps[t - d]; q = spc[t - d]; }
    __syncthreads();
    if (t >= d) { sps[t] += a; spc[t] += q; }
    __syncthreads();
  }
  int pbase = t ? sps[t - 1] : 0;
  int cbase = t ? spc[t - 1] : 0;
  offs[2 * t] = pbase;        offs[2 * t + 1] = pbase + c0;
  cursor[2 * t] = pbase;      cursor[2 * t + 1] = pbase + c0;
  if (t == 255) { offs[512] = sps[255]; nchunks[0] = spc[255]; }
  int st = pbase, ci = cbase, s = 2 * t, c = c0;
  #pragma unroll
  for (int rep = 0; rep < 2; ++rep) {
    while (c > 0) {
      int l = c > 64 ? 64 : c;
      chunk_tab[2 * ci] = (s << 16) | l;
      chunk_tab[2 * ci + 1] = st;
      st += l; c -= l; ++ci;
    }
    s = 2 * t + 1; c = c1; st = pbase + c0;
  }
  for (int i = t; i < SEGS * 3; i += 256) mean[i] = sums[i] / ((float)cnt[i / 3] + 1e-5f);
  for (int seg = t; seg < SEGS; seg += 256) {
    int b = seg >> 6;
    float s0 = 0.f, s1 = 0.f, s2 = 0.f;
    for (int kk = 0; kk < 9; ++kk) {
      int q = b * 64 + knn_I[seg * 9 + kk];
      float inv = 1.f / ((float)cnt[q] + 1e-5f);
      s0 += sums[q * 3 + 0] * inv;
      s1 += sums[q * 3 + 1] * inv;
      s2 += sums[q * 3 + 2] * inv;
    }
    s0 *= (1.f / 9.f); s1 *= (1.f / 9.f); s2 *= (1.f / 9.f);
    centerb[seg * 3 + 0] = s0;
    centerb[seg * 3 + 1] = s1;
    centerb[seg * 3 + 2] = s2;
    /* kE input: center rows (k = 512..514) + zero pad rows (515..543) */
    int ct = seg >> 4, pc = seg & 15;
    f16x8 cv = {};
    cv[0] = (f16)s0; cv[1] = (f16)s1; cv[2] = (f16)s2;
    *(f16x8*)&keinP[(size_t)((ct * 17 + 16) * 64 + pc) * 8] = cv;
    f16x8 z = {};
    #pragma unroll
    for (int ks = 1; ks < 4; ++ks)
      *(f16x8*)&keinP[(size_t)((ct * 17 + 16) * 64 + pc + 16 * ks) * 8] = z;
  }
}

/* ---------------- kernel A2: bucket points by (b,node), LDS-binned cursor --------------- */
__global__ __launch_bounds__(256) void kA2(const int* __restrict__ idx_buf, int* __restrict__ cursor,
                                           int* __restrict__ perm) {
  __shared__ int loc[64];
  __shared__ int base_s[64];
  int b = blockIdx.y;
  int t = threadIdx.x;
  if (t < 64) loc[t] = 0;
  __syncthreads();
  int n = blockIdx.x * 256 + t;
  int base = (b * NQ + n) * 3;
  int m0 = idx_buf[base + 0], m1 = idx_buf[base + 1], m2 = idx_buf[base + 2];
  int l0 = atomicAdd(&loc[m0], 1);
  int l1 = atomicAdd(&loc[m1], 1);
  int l2 = atomicAdd(&loc[m2], 1);
  __syncthreads();
  if (t < 64 && loc[t] > 0) base_s[t] = atomicAdd(&cursor[b * 64 + t], loc[t]);
  __syncthreads();
  perm[base_s[m0] + l0] = (b << 21) | (n << 8) | (0 << 6) | m0;
  perm[base_s[m1] + l1] = (b << 21) | (n << 8) | (1 << 6) | m1;
  perm[base_s[m2] + l2] = (b << 21) | (n << 8) | (2 << 6) | m2;
}

/* ---------------- kernel C: persistent MFMA PointResNet, reg-held weights --------------- */
/* 256 blocks (1/CU), 512 thr, forced 2 waves/SIMD so allocator may use 256 VGPR.          */
__global__ __launch_bounds__(512)
__attribute__((amdgpu_waves_per_eu(2, 2)))
void kC(
    const float* __restrict__ x, const float* __restrict__ sn,
    const float* __restrict__ mean, const int* __restrict__ perm,
    const int* __restrict__ chunk_tab, const int* __restrict__ nchunks,
    const float* __restrict__ w0, const float* __restrict__ b0v,
    const f16* __restrict__ w1p, const float* __restrict__ b1v,
    const f16* __restrict__ w2p, const float* __restrict__ b2v,
    const f16* __restrict__ w3p, const float* __restrict__ b3v,
    float* __restrict__ node_max, float* __restrict__ fallback) {
  __shared__ __align__(16) f16 bufA[4 * KBA * 512];   /* 40960 B */
  __shared__ __align__(16) f16 bufH1[4 * 4 * 512];    /* 16384 B */
  __shared__ float in_s[2][6][64];                    /*  3072 B */
  __shared__ float w0_s[448];                         /* w0[64][6] + b0[64] */
  __shared__ float b3_s[384];
  __shared__ int flag_s[2][64];
  int tid = threadIdx.x;
  int wid  = __builtin_amdgcn_readfirstlane(tid >> 6);
  int lane = tid & 63;
  int pcol = lane & 15;
  int g    = lane >> 4;
  int sp = tid >> 3;   /* staging: point 0..63 */
  int sc = tid & 7;    /* staging: channel 0..7 (6 used + flag + idle) */

  for (int i = tid; i < 384; i += 512) { w0_s[i] = w0[i]; b3_s[i] = b3v[i]; }
  if (tid < 64) w0_s[384 + tid] = b0v[tid];

  /* register-held weights: L2 (8 VGPR) + L4 (120 VGPR) */
  f16x8 af2h[2];
  #pragma unroll
  for (int kb = 0; kb < 2; ++kb)
    af2h[kb] = *(const f16x8*)(w1p + (size_t)((wid * 2 + kb) * 64 + lane) * 8);
  f16x8 af4h[3][KBA];
  #pragma unroll
  for (int c = 0; c < 3; ++c)
    #pragma unroll
    for (int kb = 0; kb < KBA; ++kb)
      af4h[c][kb] = *(const f16x8*)(w3p + (size_t)(((wid * 3 + c) * KBA + kb) * 64 + lane) * 8);

  int nch = nchunks[0];

  /* staging helper: chunk cidx -> buffer bi (per-thread self-sufficient, no inner barrier) */
  #define STAGE(cidx, bi) do {                                                        \
    int e0_ = chunk_tab[2 * (cidx)];                                                  \
    int st_ = chunk_tab[2 * (cidx) + 1];                                              \
    int seg_ = e0_ >> 16, len_ = e0_ & 0xffff, b_ = seg_ >> 6;                        \
    if (sc < 6) {                                                                     \
      float v_ = 0.f;                                                                 \
      if (sp < len_) {                                                                \
        int rec_ = perm[st_ + sp];                                                    \
        int n_ = (rec_ >> 8) & 0x1fff;                                                \
        if (sc < 3) v_ = x[(b_ * 3 + sc) * NQ + n_] - mean[seg_ * 3 + sc];            \
        else        v_ = sn[(b_ * 3 + (sc - 3)) * NQ + n_];                           \
      }                                                                               \
      in_s[bi][sc][sp] = v_;                                                          \
    } else if (sc == 6) {                                                             \
      int fl_ = 0;                                                                    \
      if (sp < len_) {                                                                \
        int rec_ = perm[st_ + sp];                                                    \
        fl_ = ((((rec_ >> 8) & 0x1fff) == 0) && (((rec_ >> 6) & 3) == 0)) ? 1 : 0;    \
      }                                                                               \
      flag_s[bi][sp] = fl_;                                                           \
    }                                                                                 \
  } while (0)

  if (blockIdx.x < nch) STAGE(blockIdx.x, 0);
  __syncthreads();

  int buf = 0;
  for (int blk = blockIdx.x; blk < nch; blk += 256) {
    int e0  = chunk_tab[2 * blk];
    int seg = e0 >> 16, len = e0 & 0xffff;
    int b = seg >> 6;
    /* prefetch next chunk's inputs into the other buffer (overlaps whole chunk) */
    int nxt = blk + 256;
    if (nxt < nch) STAGE(nxt, buf ^ 1);
    /* stream L3 weights early (used after 2 barriers) */
    f16x8 af3[2][4];
    #pragma unroll
    for (int s = 0; s < 2; ++s)
      #pragma unroll
      for (int kb = 0; kb < 4; ++kb)
        af3[s][kb] = *(const f16x8*)(w2p + (size_t)(((wid * 2 + s) * 4 + kb) * 64 + lane) * 8);

    /* L1 scalar 6->64 */
    {
      float a0 = in_s[buf][0][lane], a1 = in_s[buf][1][lane], a2 = in_s[buf][2][lane];
      float a3 = in_s[buf][3][lane], a4 = in_s[buf][4][lane], a5 = in_s[buf][5][lane];
      f16x8 v;
      #pragma unroll
      for (int i = 0; i < 8; ++i) {
        const float* wr = &w0_s[(wid * 8 + i) * 6];
        float s = w0_s[384 + wid * 8 + i];
        s = fmaf(wr[0], a0, s); s = fmaf(wr[1], a1, s); s = fmaf(wr[2], a2, s);
        s = fmaf(wr[3], a3, s); s = fmaf(wr[4], a4, s); s = fmaf(wr[5], a5, s);
        v[i] = (f16)fmaxf(s, 0.f);
      }
      int kb = wid >> 2, q = wid & 3;
      *(f16x8*)&bufA[(g * KBA + kb) * 512 + (pcol + 16 * q) * 8] = v;
    }
    __syncthreads();

    /* L2 MFMA 64->128 (A held) */
    f32x4 acc1[4] = {};
    #pragma unroll
    for (int kb = 0; kb < 2; ++kb) {
      #pragma unroll
      for (int pt = 0; pt < 4; ++pt) {
        f16x8 bf = *(const f16x8*)&bufA[(pt * KBA + kb) * 512 + lane * 8];
        acc1[pt] = __builtin_amdgcn_mfma_f32_16x16x32_f16(af2h[kb], bf, acc1[pt], 0, 0, 0);
      }
    }
    {
      float4 bb = *(const float4*)&b1v[wid * 16 + g * 4];
      int kbo = wid >> 1;
      int q   = ((wid & 1) << 1) + (g >> 1);
      int ee  = (g & 1) * 4;
      #pragma unroll
      for (int pt = 0; pt < 4; ++pt) {
        f16x4 v;
        v[0] = (f16)fmaxf(acc1[pt][0] + bb.x, 0.f);
        v[1] = (f16)fmaxf(acc1[pt][1] + bb.y, 0.f);
        v[2] = (f16)fmaxf(acc1[pt][2] + bb.z, 0.f);
        v[3] = (f16)fmaxf(acc1[pt][3] + bb.w, 0.f);
        *(f16x4*)&bufH1[(pt * 4 + kbo) * 512 + (pcol + 16 * q) * 8 + ee] = v;
      }
    }
    __syncthreads();

    /* L3 MFMA 128->256 (A streamed) */
    f32x4 acc2[2][4] = {};
    #pragma unroll
    for (int kb = 0; kb < 4; ++kb) {
      #pragma unroll
      for (int pt = 0; pt < 4; ++pt) {
        f16x8 bf = *(const f16x8*)&bufH1[(pt * 4 + kb) * 512 + lane * 8];
        acc2[0][pt] = __builtin_amdgcn_mfma_f32_16x16x32_f16(af3[0][kb], bf, acc2[0][pt], 0, 0, 0);
        acc2[1][pt] = __builtin_amdgcn_mfma_f32_16x16x32_f16(af3[1][kb], bf, acc2[1][pt], 0, 0, 0);
      }
    }
    {
      int kbo = 2 + wid;
      #pragma unroll
      for (int s = 0; s < 2; ++s) {
        float4 bb = *(const float4*)&b2v[(wid * 2 + s) * 16 + g * 4];
        int q  = 2 * s + (g >> 1);
        int ee = (g & 1) * 4;
        #pragma unroll
        for (int pt = 0; pt < 4; ++pt) {
          f16x4 v;
          v[0] = (f16)fmaxf(acc2[s][pt][0] + bb.x, 0.f);
          v[1] = (f16)fmaxf(acc2[s][pt][1] + bb.y, 0.f);
          v[2] = (f16)fmaxf(acc2[s][pt][2] + bb.z, 0.f);
          v[3] = (f16)fmaxf(acc2[s][pt][3] + bb.w, 0.f);
          *(f16x4*)&bufA[(pt * KBA + kbo) * 512 + (pcol + 16 * q) * 8 + ee] = v;
        }
      }
    }
    __syncthreads();

    /* L4 MFMA 320->384 (A held) */
    f32x4 acc3[3][4] = {};
    #pragma unroll
    for (int kb = 0; kb < KBA; ++kb) {
      #pragma unroll
      for (int pt = 0; pt < 4; ++pt) {
        f16x8 bf = *(const f16x8*)&bufA[(pt * KBA + kb) * 512 + lane * 8];
        acc3[0][pt] = __builtin_amdgcn_mfma_f32_16x16x32_f16(af4h[0][kb], bf, acc3[0][pt], 0, 0, 0);
        acc3[1][pt] = __builtin_amdgcn_mfma_f32_16x16x32_f16(af4h[1][kb], bf, acc3[1][pt], 0, 0, 0);
        acc3[2][pt] = __builtin_amdgcn_mfma_f32_16x16x32_f16(af4h[2][kb], bf, acc3[2][pt], 0, 0, 0);
      }
    }
    /* epilogue: bias+relu, fallback, per-channel max over 64 points, one atomic */
    {
      int fl[4], vld[4];
      #pragma unroll
      for (int pt = 0; pt < 4; ++pt) {
        fl[pt]  = flag_s[buf][pt * 16 + pcol];
        vld[pt] = (pt * 16 + pcol) < len;
      }
      #pragma unroll
      for (int c = 0; c < 3; ++c) {
        int ct = wid * 3 + c;
        #pragma unroll
        for (int j = 0; j < 4; ++j) {
          float bj = b3_s[ct * 16 + g * 4 + j];
          float vm = 0.f;
          #pragma unroll
          for (int pt = 0; pt < 4; ++pt) {
            float v = fmaxf(acc3[c][pt][j] + bj, 0.f);
            if (fl[pt]) fallback[b * 384 + ct * 16 + g * 4 + j] = v;
            if (!vld[pt]) v = 0.f;
            vm = fmaxf(vm, v);
          }
          vm = fmaxf(vm, __shfl_xor(vm, 1));
          vm = fmaxf(vm, __shfl_xor(vm, 2));
          vm = fmaxf(vm, __shfl_xor(vm, 4));
          vm = fmaxf(vm, __shfl_xor(vm, 8));
          if (pcol == 0)
            atomicMax((int*)&node_max[(size_t)seg * 384 + ct * 16 + g * 4 + j],
                      __float_as_int(vm));
        }
      }
    }
    __syncthreads();   /* bufA/bufH1 reuse + staging-write visibility for next iter */
    buf ^= 1;
  }
  #undef STAGE
}

/* ---------------- kernel Dg: gather + pack KNN input to B-fragments -------------------- */
__global__ __launch_bounds__(256) void kDg(
    const float* __restrict__ mean, const float* __restrict__ node_max,
    const float* __restrict__ fallback, const int* __restrict__ cnt,
    const int* __restrict__ knn_I, const float* __restrict__ centerb,
    f16* __restrict__ augP) {
  int idx = blockIdx.x * 256 + threadIdx.x;
  if (idx < NCOLS_D * 48) {
    int col = idx / 48;
    int rg  = idx - col * 48;
    int kk = col >> 9, seg = col & 511, b = seg >> 6;
    int nb = knn_I[seg * 9 + kk];
    const float* src = (cnt[b * 64 + nb] > 0) ? (node_max + (size_t)(b * 64 + nb) * 384)
                                              : (fallback + (size_t)b * 384);
    int r = rg * 8;
    f16x8 v;
    #pragma unroll
    for (int e = 0; e < 8; ++e) v[e] = (f16)src[r + e];
    int ct = col >> 4, pc = col & 15;
    int kb = r >> 5, ks = (r >> 3) & 3;
    *(f16x8*)&augP[(size_t)((ct * 13 + kb) * 64 + pc + 16 * ks) * 8] = v;
  } else if (idx < NCOLS_D * 48 + NCOLS_D) {
    int col = idx - NCOLS_D * 48;
    int kk = col >> 9, seg = col & 511, b = seg >> 6;
    int nb = knn_I[seg * 9 + kk];
    f16x8 v = {};
    #pragma unroll
    for (int c = 0; c < 3; ++c)
      v[c] = (f16)(mean[(b * 64 + nb) * 3 + c] - centerb[seg * 3 + c]);
    int ct = col >> 4, pc = col & 15;
    *(f16x8*)&augP[(size_t)((ct * 13 + 12) * 64 + pc) * 8] = v;
    f16x8 z = {};
    #pragma unroll
    for (int ks = 1; ks < 4; ++ks)
      *(f16x8*)&augP[(size_t)((ct * 13 + 12) * 64 + pc + 16 * ks) * 8] = z;
  }
}

/* ---------------- generic MFMA GEMM: C[64r x 64c]/block, 4 waves, no LDS ---------------- */
/* MODE 0: bias+relu -> repack f16 B-frags (NKB_OUT)
   MODE 2: bias+relu -> max over 64 cols (col-block = batch) -> outF[cb*1024+row]          */
template<int NKB_IN, int NKB_OUT, int MODE>
__global__ __launch_bounds__(256) void kGemm(
    const f16* __restrict__ Ap, const f16* __restrict__ Bp,
    const float* __restrict__ bias, f16* __restrict__ outP, float* __restrict__ outF) {
  int cb = blockIdx.x;
  int rb = blockIdx.y;
  int tid = threadIdx.x;
  int wid = __builtin_amdgcn_readfirstlane(tid >> 6);
  int lane = tid & 63;
  int rt = rb * 4 + wid;
  f32x4 acc[4] = {};
  const f16* ap = Ap + (size_t)rt * NKB_IN * 512;
  const f16* bp = Bp + (size_t)cb * 4 * NKB_IN * 512;
  #pragma unroll
  for (int kb = 0; kb < NKB_IN; ++kb) {
    f16x8 af = *(const f16x8*)(ap + (size_t)(kb * 64 + lane) * 8);
    #pragma unroll
    for (int ct = 0; ct < 4; ++ct) {
      f16x8 bf = *(const f16x8*)(bp + (size_t)((ct * NKB_IN + kb) * 64 + lane) * 8);
      acc[ct] = __builtin_amdgcn_mfma_f32_16x16x32_f16(af, bf, acc[ct], 0, 0, 0);
    }
  }
  int pcol = lane & 15, g = lane >> 4;
  float4 bb = *(const float4*)&bias[rt * 16 + g * 4];
  float bj[4] = {bb.x, bb.y, bb.z, bb.w};
  if (MODE == 0) {
    int k0 = rt * 16 + g * 4;
    int kb2 = k0 >> 5, ks2 = (k0 >> 3) & 3, ee = k0 & 7;
    #pragma unroll
    for (int ct = 0; ct < 4; ++ct) {
      f16x4 v;
      #pragma unroll
      for (int j = 0; j < 4; ++j) v[j] = (f16)fmaxf(acc[ct][j] + bj[j], 0.f);
      int ctc = cb * 4 + ct;
      *(f16x4*)&outP[(size_t)((ctc * NKB_OUT + kb2) * 64 + pcol + 16 * ks2) * 8 + ee] = v;
    }
  } else {
    #pragma unroll
    for (int j = 0; j < 4; ++j) {
      float v = fmaxf(acc[0][j] + bj[j], 0.f);
      #pragma unroll
      for (int ct = 1; ct < 4; ++ct) v = fmaxf(v, fmaxf(acc[ct][j] + bj[j], 0.f));
      v = fmaxf(v, __shfl_xor(v, 1));
      v = fmaxf(v, __shfl_xor(v, 2));
      v = fmaxf(v, __shfl_xor(v, 4));
      v = fmaxf(v, __shfl_xor(v, 8));
      if (pcol == 0) outF[cb * 1024 + rt * 16 + g * 4 + j] = v;
    }
  }
}

/* ---------------- kGemmMax9: KNN layer-2 GEMM fused with max over 9 neighbors ----------- */
/* grid (8 seg-tile groups, 8 row-blocks). A held in regs, reused across kk.
   max_kk relu(acc+b) == relu(max_kk acc + b) by monotonicity. Packs kE input frags.       */
template<int NKB_IN, int NKB_OUT>
__global__ __launch_bounds__(256) void kGemmMax9(
    const f16* __restrict__ Ap, const f16* __restrict__ Bp,
    const float* __restrict__ bias, f16* __restrict__ outP) {
  int cb = blockIdx.x;   /* 0..7: 4 seg-tiles each */
  int rb = blockIdx.y;   /* 0..7 */
  int tid = threadIdx.x;
  int wid = __builtin_amdgcn_readfirstlane(tid >> 6);
  int lane = tid & 63;
  int rt = rb * 4 + wid;
  f16x8 af[NKB_IN];
  #pragma unroll
  for (int kb = 0; kb < NKB_IN; ++kb)
    af[kb] = *(const f16x8*)(Ap + (size_t)((rt * NKB_IN + kb) * 64 + lane) * 8);
  f32x4 mx[4];
  #pragma unroll
  for (int ct = 0; ct < 4; ++ct)
    #pragma unroll
    for (int j = 0; j < 4; ++j) mx[ct][j] = -3.4e38f;
  for (int kk = 0; kk < 9; ++kk) {
    f32x4 acc[4] = {};
    const f16* bp = Bp + (size_t)(kk * 32 + cb * 4) * NKB_IN * 512;
    #pragma unroll
    for (int kb = 0; kb < NKB_IN; ++kb) {
      #pragma unroll
      for (int ct = 0; ct < 4; ++ct) {
        f16x8 bf = *(const f16x8*)(bp + (size_t)((ct * NKB_IN + kb) * 64 + lane) * 8);
        acc[ct] = __builtin_amdgcn_mfma_f32_16x16x32_f16(af[kb], bf, acc[ct], 0, 0, 0);
      }
    }
    #pragma unroll
    for (int ct = 0; ct < 4; ++ct)
      #pragma unroll
      for (int j = 0; j < 4; ++j) mx[ct][j] = fmaxf(mx[ct][j], acc[ct][j]);
  }
  int pcol = lane & 15, g = lane >> 4;
  float4 bb = *(const float4*)&bias[rt * 16 + g * 4];
  float bj[4] = {bb.x, bb.y, bb.z, bb.w};
  int k0 = rt * 16 + g * 4;
  int kb2 = k0 >> 5, ks2 = (k0 >> 3) & 3, ee = k0 & 7;
  #pragma unroll
  for (int ct = 0; ct < 4; ++ct) {
    f16x4 v;
    #pragma unroll
    for (int j = 0; j < 4; ++j) v[j] = (f16)fmaxf(mx[ct][j] + bj[j], 0.f);
    int ctc = cb * 4 + ct;
    *(f16x4*)&outP[(size_t)((ctc * NKB_OUT + kb2) * 64 + pcol + 16 * ks2) * 8 + ee] = v;
  }
}

/* ---------------- launcher -------------------------------------------------------------- */
extern "C" void kernel_launch(void* const* d_in, const int* in_sizes, int n_in,
                              void* d_out, int out_size, void* d_ws, size_t ws_size,
                              hipStream_t stream) {
  const float* x      = (const float*)d_in[0];
  const float* sn     = (const float*)d_in[1];
  const float* node   = (const float*)d_in[2];
  const int*   knn_I  = (const int*)d_in[3];
  const float* pr_w0  = (const float*)d_in[4];
  const float* pr_b0  = (const float*)d_in[5];
  const float* pr_w1  = (const float*)d_in[6];
  const float* pr_b1  = (const float*)d_in[7];
  const float* pr_w2  = (const float*)d_in[8];
  const float* pr_b2  = (const float*)d_in[9];
  const float* pr_w3  = (const float*)d_in[10];
  const float* pr_b3  = (const float*)d_in[11];
  const float* knn_w0 = (const float*)d_in[12];
  const float* knn_b0 = (const float*)d_in[13];
  const float* knn_w1 = (const float*)d_in[14];
  const float* knn_b1 = (const float*)d_in[15];
  const float* fin_w0 = (const float*)d_in[16];
  const float* fin_b0 = (const float*)d_in[17];
  const float* fin_w1 = (const float*)d_in[18];
  const float* fin_b1 = (const float*)d_in[19];
  float* out = (float*)d_out;
  char* ws = (char*)d_ws;

  int*   idx_buf   = (int*)(ws + OFF_IDX);
  int*   perm      = (int*)(ws + OFF_PERM);
  int*   cnt       = (int*)(ws + OFF_CNT);
  float* sums      = (float*)(ws + OFF_SUMS);
  int*   offs      = (int*)(ws + OFF_OFFS);
  int*   cursor    = (int*)(ws + OFF_CURSOR);
  int*   nchunks   = (int*)(ws + OFF_NCHUNK);
  int*   chunk_tab = (int*)(ws + OFF_CHUNKTAB);
  float* mean      = (float*)(ws + OFF_MEAN);
  float* fallback  = (float*)(ws + OFF_FALLBACK);
  float* node_max  = (float*)(ws + OFF_NODEMAX);
  float* centerb   = (float*)(ws + OFF_CENTER);
  f16*   w1p       = (f16*)(ws + OFF_W1P);
  f16*   w2p       = (f16*)(ws + OFF_W2P);
  f16*   w3p       = (f16*)(ws + OFF_W3P);
  f16*   knw0p     = (f16*)(ws + OFF_KNW0P);
  f16*   knw1p     = (f16*)(ws + OFF_KNW1P);
  f16*   finw0p    = (f16*)(ws + OFF_FINW0P);
  f16*   finw1p    = (f16*)(ws + OFF_FINW1P);
  f16*   augP      = (f16*)(ws + OFF_AUG);
  f16*   mid1P     = (f16*)(ws + OFF_MID1);
  f16*   keinP     = (f16*)(ws + OFF_KEIN);
  f16*   midEP     = (f16*)(ws + OFF_MIDE);

  hipMemsetAsync(ws + OFF_CNT, 0, 8192, stream);                 /* cnt + sums */
  hipMemsetAsync(ws + OFF_NODEMAX, 0, (size_t)SEGS * 384 * 4, stream);

  kW<<<7200, 256, 0, stream>>>(pr_w1, pr_w2, pr_w3, knn_w0, knn_w1, fin_w0, fin_w1,
                               w1p, w2p, w3p, knw0p, knw1p, finw0p, finw1p);

  dim3 gA(NQ / 256, BQ);
  kA<<<gA, 256, 0, stream>>>(x, node, idx_buf, cnt, sums);
  kB<<<1, 256, 0, stream>>>(cnt, sums, offs, cursor, nchunks, chunk_tab, mean, knn_I,
                            centerb, keinP);
  kA2<<<gA, 256, 0, stream>>>(idx_buf, cursor, perm);
  kC<<<256, 512, 0, stream>>>(x, sn, mean, perm, chunk_tab, nchunks,
                              pr_w0, pr_b0, w1p, pr_b1, w2p, pr_b2, w3p, pr_b3,
                              node_max, fallback);
  kDg<<<(NCOLS_D * 48 + NCOLS_D + 255) / 256, 256, 0, stream>>>(
      mean, node_max, fallback, cnt, knn_I, centerb, augP);
  kGemm<13, 16, 0><<<dim3(72, 8), 256, 0, stream>>>(knw0p, augP, knn_b0, mid1P, nullptr);
  kGemmMax9<16, 17><<<dim3(8, 8), 256, 0, stream>>>(knw1p, mid1P, knn_b1, keinP);
  kGemm<17, 24, 0><<<dim3(8, 12), 256, 0, stream>>>(finw0p, keinP, fin_b0, midEP, nullptr);
  kGemm<24, 0, 2><<<dim3(8, 16), 256, 0, stream>>>(finw1p, midEP, fin_b1, nullptr, out);
}

// Round 7
// 249.571 us; speedup vs baseline: 1.6208x; 1.6208x over previous
//
#include <hip/hip_runtime.h>

typedef unsigned short u16;
typedef unsigned int   u32;
typedef _Float16 f16;
typedef _Float16 f16x8 __attribute__((ext_vector_type(8)));
typedef _Float16 f16x4 __attribute__((ext_vector_type(4)));
typedef float    f32x4 __attribute__((ext_vector_type(4)));

#define BQ 8
#define NQ 8192
#define MQ 64
#define SEGS (BQ*MQ)        /* 512 */
#define MAXCHUNK 3584
#define KBA 10              /* k-blocks in concat(h0,h2) = 320/32 */
#define NCOLS_D 4608        /* 9*512 cols for KNN module, layout [kk][seg] */

/* ---- workspace layout (bytes) ---- */
#define OFF_IDX      (size_t)0
#define OFF_PERM     (size_t)786432
#define OFF_CNT      (size_t)1572864
#define OFF_SUMS     (size_t)1574912
#define OFF_OFFS     (size_t)1581056
#define OFF_CURSOR   (size_t)1583360
#define OFF_NCHUNK   (size_t)1585408
#define OFF_CHUNKTAB (size_t)1585664
#define OFF_MEAN     (size_t)1614336
#define OFF_FALLBACK (size_t)1620480
#define OFF_NODEMAX  (size_t)1632768
#define OFF_CENTER   (size_t)2419200
#define OFF_W1P      (size_t)2425344
#define OFF_W2P      (size_t)2441728
#define OFF_W3P      (size_t)2507264
#define OFF_KNW0P    (size_t)2753024
#define OFF_KNW1P    (size_t)3179008
#define OFF_FINW0P   (size_t)3703296
#define OFF_FINW1P   (size_t)4538880
#define OFF_AUG      (size_t)6111744
#define OFF_MID1     (size_t)9945600
#define OFF_GBUF     (size_t)14664192
#define OFF_KEIN     (size_t)19382784
#define OFF_MIDE     (size_t)19939840

/* ---------------- kernel W: all weight packs (A-fragment layout, f16) ------------------- */
__device__ __forceinline__ void wpack(const float* __restrict__ W, f16* __restrict__ out,
                                      int K, int KB, int NF, int idx) {
  int e  = idx & 7;
  int l  = (idx >> 3) & 63;
  int kb = (idx >> 9) % KB;
  int rt = idx / (KB << 9);
  int row = rt * 16 + (l & 15);
  int c = kb * 32 + ((l >> 4) << 3) + e;
  int oc;
  if (NF < 0) oc = (c < K) ? c : -1;
  else        oc = (c < NF) ? (3 + c) : ((c < NF + 3) ? (c - NF) : -1);
  out[idx] = (oc >= 0) ? (f16)W[row * K + oc] : (f16)0.f;
}
__global__ __launch_bounds__(256) void kW(
    const float* pr_w1, const float* pr_w2, const float* pr_w3,
    const float* knn_w0, const float* knn_w1, const float* fin_w0, const float* fin_w1,
    f16* w1p, f16* w2p, f16* w3p, f16* knw0p, f16* knw1p, f16* finw0p, f16* finw1p) {
  int blk = blockIdx.x;
  int t = threadIdx.x;
  if (blk < 32)        wpack(pr_w1,  w1p,   64,  2, -1, blk * 256 + t);
  else if (blk < 160)  wpack(pr_w2,  w2p,  128,  4, -1, (blk - 32) * 256 + t);
  else if (blk < 640)  wpack(pr_w3,  w3p,  320, 10, -1, (blk - 160) * 256 + t);
  else if (blk < 1472) wpack(knn_w0, knw0p, 387, 13, 384, (blk - 640) * 256 + t);
  else if (blk < 2496) wpack(knn_w1, knw1p, 512, 16, -1, (blk - 1472) * 256 + t);
  else if (blk < 4128) wpack(fin_w0, finw0p, 515, 17, 512, (blk - 2496) * 256 + t);
  else                 wpack(fin_w1, finw1p, 768, 24, -1, (blk - 4128) * 256 + t);
}

/* ---------------- kernel A: top-3 nearest SOM nodes + LDS-binned count/sum ------------- */
__global__ __launch_bounds__(256) void kA(const float* __restrict__ x, const float* __restrict__ node,
                                          int* __restrict__ idx_buf, int* __restrict__ cnt,
                                          float* __restrict__ sums) {
#pragma clang fp contract(off)
  __shared__ float ns[3][64];
  __shared__ int cbin[64];
  __shared__ float sbin[3][64];
  int b = blockIdx.y;
  int t = threadIdx.x;
  if (t < 192) { int c = t >> 6, m = t & 63; ns[c][m] = node[(b * 3 + c) * 64 + m]; }
  if (t < 64) { cbin[t] = 0; sbin[0][t] = 0.f; sbin[1][t] = 0.f; sbin[2][t] = 0.f; }
  __syncthreads();
  int n = blockIdx.x * 256 + t;
  float x0 = x[(b * 3 + 0) * NQ + n];
  float x1 = x[(b * 3 + 1) * NQ + n];
  float x2 = x[(b * 3 + 2) * NQ + n];
  float d0 = 3.4e38f, d1 = 3.4e38f, d2 = 3.4e38f;
  int i0 = 0, i1 = 0, i2 = 0;
  for (int m = 0; m < 64; ++m) {
    float da = ns[0][m] - x0;
    float db = ns[1][m] - x1;
    float dc = ns[2][m] - x2;
    float d = da * da + db * db + dc * dc;
    if (d < d0)      { d2 = d1; i2 = i1; d1 = d0; i1 = i0; d0 = d; i0 = m; }
    else if (d < d1) { d2 = d1; i2 = i1; d1 = d;  i1 = m; }
    else if (d < d2) { d2 = d;  i2 = m; }
  }
  int base = (b * NQ + n) * 3;
  idx_buf[base + 0] = i0; idx_buf[base + 1] = i1; idx_buf[base + 2] = i2;
  int ms[3] = {i0, i1, i2};
  #pragma unroll
  for (int j = 0; j < 3; ++j) {
    int m = ms[j];
    atomicAdd(&cbin[m], 1);
    atomicAdd(&sbin[0][m], x0);
    atomicAdd(&sbin[1][m], x1);
    atomicAdd(&sbin[2][m], x2);
  }
  __syncthreads();
  if (t < 64 && cbin[t] > 0) {
    atomicAdd(&cnt[b * 64 + t], cbin[t]);
    atomicAdd(&sums[(b * 64 + t) * 3 + 0], sbin[0][t]);
    atomicAdd(&sums[(b * 64 + t) * 3 + 1], sbin[1][t]);
    atomicAdd(&sums[(b * 64 + t) * 3 + 2], sbin[2][t]);
  }
}

/* ---------------- kernel B: scans, chunk table, means, centers, kein center-rows -------- */
__global__ __launch_bounds__(256) void kB(const int* __restrict__ cnt, const float* __restrict__ sums,
                                          int* __restrict__ offs, int* __restrict__ cursor,
                                          int* __restrict__ nchunks, int* __restrict__ chunk_tab,
                                          float* __restrict__ mean, const int* __restrict__ knn_I,
                                          float* __restrict__ centerb, f16* __restrict__ keinP) {
  __shared__ int sps[256], spc[256];
  int t = threadIdx.x;
  int c0 = cnt[2 * t], c1 = cnt[2 * t + 1];
  sps[t] = c0 + c1;
  spc[t] = ((c0 + 63) >> 6) + ((c1 + 63) >> 6);
  __syncthreads();
  for (int d = 1; d < 256; d <<= 1) {
    int a = 0, q = 0;
    if (t >= d) { a = sps[t - d]; q = spc[t - d]; }
    __syncthreads();
    if (t >= d) { sps[t] += a; spc[t] += q; }
    __syncthreads();
  }
  int pbase = t ? sps[t - 1] : 0;
  int cbase = t ? spc[t - 1] : 0;
  offs[2 * t] = pbase;        offs[2 * t + 1] = pbase + c0;
  cursor[2 * t] = pbase;      cursor[2 * t + 1] = pbase + c0;
  if (t == 255) { offs[512] = sps[255]; nchunks[0] = spc[255]; }
  int st = pbase, ci = cbase, s = 2 * t, c = c0;
  #pragma unroll
  for (int rep = 0; rep < 2; ++rep) {
    while (c > 0) {
      int l = c > 64 ? 64 : c;
      chunk_tab[2 * ci] = (s << 16) | l;
      chunk_tab[2 * ci + 1] = st;
      st += l; c -= l; ++ci;
    }
    s = 2 * t + 1; c = c1; st = pbase + c0;
  }
  for (int i = t; i < SEGS * 3; i += 256) mean[i] = sums[i] / ((float)cnt[i / 3] + 1e-5f);
  for (int seg = t; seg < SEGS; seg += 256) {
    int b = seg >> 6;
    float s0 = 0.f, s1 = 0.f, s2 = 0.f;
    for (int kk = 0; kk < 9; ++kk) {
      int q = b * 64 + knn_I[seg * 9 + kk];
      float inv = 1.f / ((float)cnt[q] + 1e-5f);
      s0 += sums[q * 3 + 0] * inv;
      s1 += sums[q * 3 + 1] * inv;
      s2 += sums[q * 3 + 2] * inv;
    }
    s0 *= (1.f / 9.f); s1 *= (1.f / 9.f); s2 *= (1.f / 9.f);
    centerb[seg * 3 + 0] = s0;
    centerb[seg * 3 + 1] = s1;
    centerb[seg * 3 + 2] = s2;
    /* kE input: center rows (k = 512..514) + zero pad rows (515..543) */
    int ct = seg >> 4, pc = seg & 15;
    f16x8 cv = {};
    cv[0] = (f16)s0; cv[1] = (f16)s1; cv[2] = (f16)s2;
    *(f16x8*)&keinP[(size_t)((ct * 17 + 16) * 64 + pc) * 8] = cv;
    f16x8 z = {};
    #pragma unroll
    for (int ks = 1; ks < 4; ++ks)
      *(f16x8*)&keinP[(size_t)((ct * 17 + 16) * 64 + pc + 16 * ks) * 8] = z;
  }
}

/* ---------------- kernel A2: bucket points by (b,node), LDS-binned cursor --------------- */
__global__ __launch_bounds__(256) void kA2(const int* __restrict__ idx_buf, int* __restrict__ cursor,
                                           int* __restrict__ perm) {
  __shared__ int loc[64];
  __shared__ int base_s[64];
  int b = blockIdx.y;
  int t = threadIdx.x;
  if (t < 64) loc[t] = 0;
  __syncthreads();
  int n = blockIdx.x * 256 + t;
  int base = (b * NQ + n) * 3;
  int m0 = idx_buf[base + 0], m1 = idx_buf[base + 1], m2 = idx_buf[base + 2];
  int l0 = atomicAdd(&loc[m0], 1);
  int l1 = atomicAdd(&loc[m1], 1);
  int l2 = atomicAdd(&loc[m2], 1);
  __syncthreads();
  if (t < 64 && loc[t] > 0) base_s[t] = atomicAdd(&cursor[b * 64 + t], loc[t]);
  __syncthreads();
  perm[base_s[m0] + l0] = (b << 21) | (n << 8) | (0 << 6) | m0;
  perm[base_s[m1] + l1] = (b << 21) | (n << 8) | (1 << 6) | m1;
  perm[base_s[m2] + l2] = (b << 21) | (n << 8) | (2 << 6) | m2;
}

/* ---------------- kernel C: fused MFMA PointResNet + per-node scatter-max --------------- */
/* round-4 version: 1 chunk per block, streamed weights, 56 VGPR, ~2 blocks/CU            */
__global__ __launch_bounds__(512) void kC(
    const float* __restrict__ x, const float* __restrict__ sn,
    const float* __restrict__ mean, const int* __restrict__ perm,
    const int* __restrict__ chunk_tab, const int* __restrict__ nchunks,
    const float* __restrict__ w0, const float* __restrict__ b0v,
    const f16* __restrict__ w1p, const float* __restrict__ b1v,
    const f16* __restrict__ w2p, const float* __restrict__ b2v,
    const f16* __restrict__ w3p, const float* __restrict__ b3v,
    float* __restrict__ node_max, float* __restrict__ fallback) {
  __shared__ __align__(16) f16 bufA[4 * KBA * 64 * 8];
  __shared__ __align__(16) f16 bufH1[4 * 4 * 64 * 8];
  __shared__ float in_s[6][64];
  __shared__ int flag_s[64];
  int blk = blockIdx.x;
  if (blk >= nchunks[0]) return;
  int e0    = chunk_tab[2 * blk];
  int start = chunk_tab[2 * blk + 1];
  int seg = e0 >> 16, len = e0 & 0xffff;
  int b = seg >> 6;
  int tid = threadIdx.x;
  if (tid < 64) {
    float v0 = 0, v1 = 0, v2 = 0, v3 = 0, v4 = 0, v5 = 0;
    int fl = 0;
    if (tid < len) {
      int rec = perm[start + tid];
      int n = (rec >> 8) & 0x1fff;
      int j = (rec >> 6) & 3;
      const float* xb = x  + (size_t)b * 3 * NQ;
      const float* sb = sn + (size_t)b * 3 * NQ;
      v0 = xb[n]          - mean[seg * 3 + 0];
      v1 = xb[NQ + n]     - mean[seg * 3 + 1];
      v2 = xb[2 * NQ + n] - mean[seg * 3 + 2];
      v3 = sb[n]; v4 = sb[NQ + n]; v5 = sb[2 * NQ + n];
      fl = (n == 0 && j == 0) ? 1 : 0;
    }
    in_s[0][tid] = v0; in_s[1][tid] = v1; in_s[2][tid] = v2;
    in_s[3][tid] = v3; in_s[4][tid] = v4; in_s[5][tid] = v5;
    flag_s[tid] = fl;
  }
  __syncthreads();
  int wid  = __builtin_amdgcn_readfirstlane(tid >> 6);
  int lane = tid & 63;
  int pcol = lane & 15;
  int g    = lane >> 4;

  /* L1 scalar 6->64 */
  {
    float a0 = in_s[0][lane], a1 = in_s[1][lane], a2 = in_s[2][lane];
    float a3 = in_s[3][lane], a4 = in_s[4][lane], a5 = in_s[5][lane];
    f16x8 v;
    #pragma unroll
    for (int i = 0; i < 8; ++i) {
      const float* wr = w0 + (wid * 8 + i) * 6;
      float s = b0v[wid * 8 + i];
      s = fmaf(wr[0], a0, s); s = fmaf(wr[1], a1, s); s = fmaf(wr[2], a2, s);
      s = fmaf(wr[3], a3, s); s = fmaf(wr[4], a4, s); s = fmaf(wr[5], a5, s);
      v[i] = (f16)fmaxf(s, 0.f);
    }
    int kb = wid >> 2, q = wid & 3;
    *(f16x8*)&bufA[(((lane >> 4) * KBA + kb) * 64 + pcol + 16 * q) * 8] = v;
  }
  __syncthreads();

  /* L2 MFMA 64->128 */
  f32x4 acc1[4] = {};
  #pragma unroll
  for (int kb = 0; kb < 2; ++kb) {
    f16x8 af = *(const f16x8*)(w1p + (size_t)((wid * 2 + kb) * 64 + lane) * 8);
    #pragma unroll
    for (int pt = 0; pt < 4; ++pt) {
      f16x8 bf = *(const f16x8*)&bufA[((pt * KBA + kb) * 64 + lane) * 8];
      acc1[pt] = __builtin_amdgcn_mfma_f32_16x16x32_f16(af, bf, acc1[pt], 0, 0, 0);
    }
  }
  {
    float4 bb = *(const float4*)&b1v[wid * 16 + g * 4];
    int kbo = wid >> 1;
    int q   = ((wid & 1) << 1) + (g >> 1);
    int ee  = (g & 1) * 4;
    #pragma unroll
    for (int pt = 0; pt < 4; ++pt) {
      f16x4 v;
      v[0] = (f16)fmaxf(acc1[pt][0] + bb.x, 0.f);
      v[1] = (f16)fmaxf(acc1[pt][1] + bb.y, 0.f);
      v[2] = (f16)fmaxf(acc1[pt][2] + bb.z, 0.f);
      v[3] = (f16)fmaxf(acc1[pt][3] + bb.w, 0.f);
      *(f16x4*)&bufH1[((pt * 4 + kbo) * 64 + pcol + 16 * q) * 8 + ee] = v;
    }
  }
  __syncthreads();

  /* L3 MFMA 128->256 */
  f32x4 acc2[2][4] = {};
  #pragma unroll
  for (int kb = 0; kb < 4; ++kb) {
    f16x8 af0 = *(const f16x8*)(w2p + (size_t)(((wid * 2 + 0) * 4 + kb) * 64 + lane) * 8);
    f16x8 af1 = *(const f16x8*)(w2p + (size_t)(((wid * 2 + 1) * 4 + kb) * 64 + lane) * 8);
    #pragma unroll
    for (int pt = 0; pt < 4; ++pt) {
      f16x8 bf = *(const f16x8*)&bufH1[((pt * 4 + kb) * 64 + lane) * 8];
      acc2[0][pt] = __builtin_amdgcn_mfma_f32_16x16x32_f16(af0, bf, acc2[0][pt], 0, 0, 0);
      acc2[1][pt] = __builtin_amdgcn_mfma_f32_16x16x32_f16(af1, bf, acc2[1][pt], 0, 0, 0);
    }
  }
  {
    int kbo = 2 + wid;
    #pragma unroll
    for (int s = 0; s < 2; ++s) {
      float4 bb = *(const float4*)&b2v[(wid * 2 + s) * 16 + g * 4];
      int q  = 2 * s + (g >> 1);
      int ee = (g & 1) * 4;
      #pragma unroll
      for (int pt = 0; pt < 4; ++pt) {
        f16x4 v;
        v[0] = (f16)fmaxf(acc2[s][pt][0] + bb.x, 0.f);
        v[1] = (f16)fmaxf(acc2[s][pt][1] + bb.y, 0.f);
        v[2] = (f16)fmaxf(acc2[s][pt][2] + bb.z, 0.f);
        v[3] = (f16)fmaxf(acc2[s][pt][3] + bb.w, 0.f);
        *(f16x4*)&bufA[((pt * KBA + kbo) * 64 + pcol + 16 * q) * 8 + ee] = v;
      }
    }
  }
  __syncthreads();

  /* L4 MFMA 320->384 */
  f32x4 acc3[3][4] = {};
  #pragma unroll
  for (int kb = 0; kb < KBA; ++kb) {
    f16x8 af0 = *(const f16x8*)(w3p + (size_t)(((wid * 3 + 0) * KBA + kb) * 64 + lane) * 8);
    f16x8 af1 = *(const f16x8*)(w3p + (size_t)(((wid * 3 + 1) * KBA + kb) * 64 + lane) * 8);
    f16x8 af2 = *(const f16x8*)(w3p + (size_t)(((wid * 3 + 2) * KBA + kb) * 64 + lane) * 8);
    #pragma unroll
    for (int pt = 0; pt < 4; ++pt) {
      f16x8 bf = *(const f16x8*)&bufA[((pt * KBA + kb) * 64 + lane) * 8];
      acc3[0][pt] = __builtin_amdgcn_mfma_f32_16x16x32_f16(af0, bf, acc3[0][pt], 0, 0, 0);
      acc3[1][pt] = __builtin_amdgcn_mfma_f32_16x16x32_f16(af1, bf, acc3[1][pt], 0, 0, 0);
      acc3[2][pt] = __builtin_amdgcn_mfma_f32_16x16x32_f16(af2, bf, acc3[2][pt], 0, 0, 0);
    }
  }
  {
    int fl[4], vld[4];
    #pragma unroll
    for (int pt = 0; pt < 4; ++pt) {
      fl[pt]  = flag_s[pt * 16 + pcol];
      vld[pt] = (pt * 16 + pcol) < len;
    }
    #pragma unroll
    for (int c = 0; c < 3; ++c) {
      int ct = wid * 3 + c;
      float4 bb = *(const float4*)&b3v[ct * 16 + g * 4];
      float bj[4] = {bb.x, bb.y, bb.z, bb.w};
      #pragma unroll
      for (int j = 0; j < 4; ++j) {
        float vm = 0.f;
        #pragma unroll
        for (int pt = 0; pt < 4; ++pt) {
          float v = fmaxf(acc3[c][pt][j] + bj[j], 0.f);
          if (fl[pt]) fallback[b * 384 + ct * 16 + g * 4 + j] = v;
          if (!vld[pt]) v = 0.f;
          vm = fmaxf(vm, v);
        }
        vm = fmaxf(vm, __shfl_xor(vm, 1));
        vm = fmaxf(vm, __shfl_xor(vm, 2));
        vm = fmaxf(vm, __shfl_xor(vm, 4));
        vm = fmaxf(vm, __shfl_xor(vm, 8));
        if (pcol == 0)
          atomicMax((int*)&node_max[(size_t)seg * 384 + ct * 16 + g * 4 + j],
                    __float_as_int(vm));
      }
    }
  }
}

/* ---------------- kernel Dg: gather + pack KNN input to B-fragments -------------------- */
__global__ __launch_bounds__(256) void kDg(
    const float* __restrict__ mean, const float* __restrict__ node_max,
    const float* __restrict__ fallback, const int* __restrict__ cnt,
    const int* __restrict__ knn_I, const float* __restrict__ centerb,
    f16* __restrict__ augP) {
  int idx = blockIdx.x * 256 + threadIdx.x;
  if (idx < NCOLS_D * 48) {
    int col = idx / 48;
    int rg  = idx - col * 48;
    int kk = col >> 9, seg = col & 511, b = seg >> 6;
    int nb = knn_I[seg * 9 + kk];
    const float* src = (cnt[b * 64 + nb] > 0) ? (node_max + (size_t)(b * 64 + nb) * 384)
                                              : (fallback + (size_t)b * 384);
    int r = rg * 8;
    f16x8 v;
    #pragma unroll
    for (int e = 0; e < 8; ++e) v[e] = (f16)src[r + e];
    int ct = col >> 4, pc = col & 15;
    int kb = r >> 5, ks = (r >> 3) & 3;
    *(f16x8*)&augP[(size_t)((ct * 13 + kb) * 64 + pc + 16 * ks) * 8] = v;
  } else if (idx < NCOLS_D * 48 + NCOLS_D) {
    int col = idx - NCOLS_D * 48;
    int kk = col >> 9, seg = col & 511, b = seg >> 6;
    int nb = knn_I[seg * 9 + kk];
    f16x8 v = {};
    #pragma unroll
    for (int c = 0; c < 3; ++c)
      v[c] = (f16)(mean[(b * 64 + nb) * 3 + c] - centerb[seg * 3 + c]);
    int ct = col >> 4, pc = col & 15;
    *(f16x8*)&augP[(size_t)((ct * 13 + 12) * 64 + pc) * 8] = v;
    f16x8 z = {};
    #pragma unroll
    for (int ks = 1; ks < 4; ++ks)
      *(f16x8*)&augP[(size_t)((ct * 13 + 12) * 64 + pc + 16 * ks) * 8] = z;
  }
}

/* ---------------- generic MFMA GEMM: C[64r x 64c]/block, 4 waves, no LDS ---------------- */
/* MODE 0: bias+relu -> repack f16 B-frags (NKB_OUT)
   MODE 1: bias+relu -> gbuf[col][512]
   MODE 2: bias+relu -> max over 64 cols (col-block = batch) -> outF[cb*1024+row]
   launch_bounds(256,1): min 1 wave/EU so allocator may use many VGPRs to pipeline loads. */
template<int NKB_IN, int NKB_OUT, int MODE>
__global__ __launch_bounds__(256, 1) void kGemm(
    const f16* __restrict__ Ap, const f16* __restrict__ Bp,
    const float* __restrict__ bias, f16* __restrict__ outP, float* __restrict__ outF) {
  int cb = blockIdx.x;
  int rb = blockIdx.y;
  int tid = threadIdx.x;
  int wid = __builtin_amdgcn_readfirstlane(tid >> 6);
  int lane = tid & 63;
  int rt = rb * 4 + wid;
  f32x4 acc[4] = {};
  const f16* ap = Ap + (size_t)rt * NKB_IN * 512;
  const f16* bp = Bp + (size_t)cb * 4 * NKB_IN * 512;
  #pragma unroll
  for (int kb = 0; kb < NKB_IN; ++kb) {
    f16x8 af = *(const f16x8*)(ap + (size_t)(kb * 64 + lane) * 8);
    #pragma unroll
    for (int ct = 0; ct < 4; ++ct) {
      f16x8 bf = *(const f16x8*)(bp + (size_t)((ct * NKB_IN + kb) * 64 + lane) * 8);
      acc[ct] = __builtin_amdgcn_mfma_f32_16x16x32_f16(af, bf, acc[ct], 0, 0, 0);
    }
  }
  int pcol = lane & 15, g = lane >> 4;
  float4 bb = *(const float4*)&bias[rt * 16 + g * 4];
  float bj[4] = {bb.x, bb.y, bb.z, bb.w};
  if (MODE == 0) {
    int k0 = rt * 16 + g * 4;
    int kb2 = k0 >> 5, ks2 = (k0 >> 3) & 3, ee = k0 & 7;
    #pragma unroll
    for (int ct = 0; ct < 4; ++ct) {
      f16x4 v;
      #pragma unroll
      for (int j = 0; j < 4; ++j) v[j] = (f16)fmaxf(acc[ct][j] + bj[j], 0.f);
      int ctc = cb * 4 + ct;
      *(f16x4*)&outP[(size_t)((ctc * NKB_OUT + kb2) * 64 + pcol + 16 * ks2) * 8 + ee] = v;
    }
  } else if (MODE == 1) {
    #pragma unroll
    for (int ct = 0; ct < 4; ++ct) {
      f16x4 v;
      #pragma unroll
      for (int j = 0; j < 4; ++j) v[j] = (f16)fmaxf(acc[ct][j] + bj[j], 0.f);
      int col = cb * 64 + ct * 16 + pcol;
      *(f16x4*)&outP[(size_t)col * 512 + rt * 16 + g * 4] = v;
    }
  } else {
    #pragma unroll
    for (int j = 0; j < 4; ++j) {
      float v = fmaxf(acc[0][j] + bj[j], 0.f);
      #pragma unroll
      for (int ct = 1; ct < 4; ++ct) v = fmaxf(v, fmaxf(acc[ct][j] + bj[j], 0.f));
      v = fmaxf(v, __shfl_xor(v, 1));
      v = fmaxf(v, __shfl_xor(v, 2));
      v = fmaxf(v, __shfl_xor(v, 4));
      v = fmaxf(v, __shfl_xor(v, 8));
      if (pcol == 0) outF[cb * 1024 + rt * 16 + g * 4 + j] = v;
    }
  }
}

/* ---------------- kernel Dmax: max over 9 kk -> kE input pack (feature rows) ------------ */
__global__ __launch_bounds__(256) void kDmax(const f16* __restrict__ gbuf,
                                             f16* __restrict__ keinP) {
  int idx = blockIdx.x * 256 + threadIdx.x;
  if (idx >= SEGS * 64) return;
  int seg = idx >> 6;
  int rg  = idx & 63;
  int r = rg * 8;
  float m[8] = {};
  for (int kk = 0; kk < 9; ++kk) {
    f16x8 gv = *(const f16x8*)&gbuf[(size_t)(kk * 512 + seg) * 512 + r];
    #pragma unroll
    for (int e = 0; e < 8; ++e) m[e] = fmaxf(m[e], (float)gv[e]);
  }
  f16x8 v;
  #pragma unroll
  for (int e = 0; e < 8; ++e) v[e] = (f16)m[e];
  int ct = seg >> 4, pc = seg & 15;
  int kb = r >> 5, ks = (r >> 3) & 3;
  *(f16x8*)&keinP[(size_t)((ct * 17 + kb) * 64 + pc + 16 * ks) * 8] = v;
}

/* ---------------- launcher -------------------------------------------------------------- */
extern "C" void kernel_launch(void* const* d_in, const int* in_sizes, int n_in,
                              void* d_out, int out_size, void* d_ws, size_t ws_size,
                              hipStream_t stream) {
  const float* x      = (const float*)d_in[0];
  const float* sn     = (const float*)d_in[1];
  const float* node   = (const float*)d_in[2];
  const int*   knn_I  = (const int*)d_in[3];
  const float* pr_w0  = (const float*)d_in[4];
  const float* pr_b0  = (const float*)d_in[5];
  const float* pr_w1  = (const float*)d_in[6];
  const float* pr_b1  = (const float*)d_in[7];
  const float* pr_w2  = (const float*)d_in[8];
  const float* pr_b2  = (const float*)d_in[9];
  const float* pr_w3  = (const float*)d_in[10];
  const float* pr_b3  = (const float*)d_in[11];
  const float* knn_w0 = (const float*)d_in[12];
  const float* knn_b0 = (const float*)d_in[13];
  const float* knn_w1 = (const float*)d_in[14];
  const float* knn_b1 = (const float*)d_in[15];
  const float* fin_w0 = (const float*)d_in[16];
  const float* fin_b0 = (const float*)d_in[17];
  const float* fin_w1 = (const float*)d_in[18];
  const float* fin_b1 = (const float*)d_in[19];
  float* out = (float*)d_out;
  char* ws = (char*)d_ws;

  int*   idx_buf   = (int*)(ws + OFF_IDX);
  int*   perm      = (int*)(ws + OFF_PERM);
  int*   cnt       = (int*)(ws + OFF_CNT);
  float* sums      = (float*)(ws + OFF_SUMS);
  int*   offs      = (int*)(ws + OFF_OFFS);
  int*   cursor    = (int*)(ws + OFF_CURSOR);
  int*   nchunks   = (int*)(ws + OFF_NCHUNK);
  int*   chunk_tab = (int*)(ws + OFF_CHUNKTAB);
  float* mean      = (float*)(ws + OFF_MEAN);
  float* fallback  = (float*)(ws + OFF_FALLBACK);
  float* node_max  = (float*)(ws + OFF_NODEMAX);
  float* centerb   = (float*)(ws + OFF_CENTER);
  f16*   w1p       = (f16*)(ws + OFF_W1P);
  f16*   w2p       = (f16*)(ws + OFF_W2P);
  f16*   w3p       = (f16*)(ws + OFF_W3P);
  f16*   knw0p     = (f16*)(ws + OFF_KNW0P);
  f16*   knw1p     = (f16*)(ws + OFF_KNW1P);
  f16*   finw0p    = (f16*)(ws + OFF_FINW0P);
  f16*   finw1p    = (f16*)(ws + OFF_FINW1P);
  f16*   augP      = (f16*)(ws + OFF_AUG);
  f16*   mid1P     = (f16*)(ws + OFF_MID1);
  f16*   gbuf      = (f16*)(ws + OFF_GBUF);
  f16*   keinP     = (f16*)(ws + OFF_KEIN);
  f16*   midEP     = (f16*)(ws + OFF_MIDE);

  hipMemsetAsync(ws + OFF_CNT, 0, 8192, stream);                 /* cnt + sums */
  hipMemsetAsync(ws + OFF_NODEMAX, 0, (size_t)SEGS * 384 * 4, stream);

  kW<<<7200, 256, 0, stream>>>(pr_w1, pr_w2, pr_w3, knn_w0, knn_w1, fin_w0, fin_w1,
                               w1p, w2p, w3p, knw0p, knw1p, finw0p, finw1p);

  dim3 gA(NQ / 256, BQ);
  kA<<<gA, 256, 0, stream>>>(x, node, idx_buf, cnt, sums);
  kB<<<1, 256, 0, stream>>>(cnt, sums, offs, cursor, nchunks, chunk_tab, mean, knn_I,
                            centerb, keinP);
  kA2<<<gA, 256, 0, stream>>>(idx_buf, cursor, perm);
  kC<<<MAXCHUNK, 512, 0, stream>>>(x, sn, mean, perm, chunk_tab, nchunks,
                                   pr_w0, pr_b0, w1p, pr_b1, w2p, pr_b2, w3p, pr_b3,
                                   node_max, fallback);
  kDg<<<(NCOLS_D * 48 + NCOLS_D + 255) / 256, 256, 0, stream>>>(
      mean, node_max, fallback, cnt, knn_I, centerb, augP);
  kGemm<13, 16, 0><<<dim3(72, 8), 256, 0, stream>>>(knw0p, augP, knn_b0, mid1P, nullptr);
  kGemm<16, 0, 1><<<dim3(72, 8), 256, 0, stream>>>(knw1p, mid1P, knn_b1, gbuf, nullptr);
  kDmax<<<SEGS * 64 / 256, 256, 0, stream>>>(gbuf, keinP);
  kGemm<17, 24, 0><<<dim3(8, 12), 256, 0, stream>>>(finw0p, keinP, fin_b0, midEP, nullptr);
  kGemm<24, 0, 2><<<dim3(8, 16), 256, 0, stream>>>(finw1p, midEP, fin_b1, nullptr, out);
}